// Round 7
// baseline (276.016 us; speedup 1.0000x reference)
//
#include <hip/hip_runtime.h>
#include <hip/hip_bf16.h>
#include <stdint.h>

#define B_ROWS 16384
#define D_IN   512
#define H_DIM  1024
#define K_TOT  1536
#define NKT    48          // K-tiles of 32

typedef __attribute__((ext_vector_type(8)))  short bf16x8;
typedef __attribute__((ext_vector_type(16))) float f32x16;
typedef __attribute__((ext_vector_type(4)))  float float4v;
typedef __attribute__((ext_vector_type(8)))  unsigned short u16x8;

__device__ __forceinline__ unsigned short f2bf(float f) {
    uint32_t u = __float_as_uint(f);
    u = (u + 0x7FFFu + ((u >> 16) & 1u)) >> 16;   // RNE
    return (unsigned short)u;
}

// ---------------------------------------------------------------------------
// Ag in FRAGMENT-LINEAR TILED order (unchanged):
//   granule g = ((bm*48 + tile)*16 + chunk)*64 + lane   (16 B each)
//   lane l, elem j: row = bm*256 + (chunk>>1)*32 + (l&31)
//                   k   = tile*32 + (chunk&1)*16 + (l>>5)*8 + j
// ---------------------------------------------------------------------------
__global__ void cvt_A(const float* __restrict__ x, const float* __restrict__ h,
                      unsigned short* __restrict__ Ag) {
    int t     = blockIdx.x * blockDim.x + threadIdx.x;
    int lane  = t & 63;
    int chunk = (t >> 6) & 15;
    int rest  = t >> 10;            // bm*48 + tile
    int tile  = rest % 48;
    int bm    = rest / 48;
    int row   = bm * 256 + (chunk >> 1) * 32 + (lane & 31);
    int k     = tile * 32 + (chunk & 1) * 16 + (lane >> 5) * 8;
    const float* src = (k < 512) ? (x + (size_t)row * D_IN + k)
                                 : (h + (size_t)row * H_DIM + (k - 512));
    float4v v0 = *(const float4v*)(src);
    float4v v1 = *(const float4v*)(src + 4);
    u16x8 o;
    o[0] = f2bf(v0[0]); o[1] = f2bf(v0[1]); o[2] = f2bf(v0[2]); o[3] = f2bf(v0[3]);
    o[4] = f2bf(v1[0]); o[5] = f2bf(v1[1]); o[6] = f2bf(v1[2]); o[7] = f2bf(v1[3]);
    *(u16x8*)(Ag + (size_t)t * 8) = o;
}

// ---------------------------------------------------------------------------
// Bg fragment-linear tiled, gate-interleaved cols (granularity 32):
//   col c = (h>>5)*128 + gate*32 + (h&31)
// ---------------------------------------------------------------------------
__global__ void cvt_B(const float* __restrict__ Ui, const float* __restrict__ Uf,
                      const float* __restrict__ Uo, const float* __restrict__ Uc,
                      const float* __restrict__ Wi, const float* __restrict__ Wf,
                      const float* __restrict__ Wo, const float* __restrict__ Wc,
                      unsigned short* __restrict__ Bg) {
    int t     = blockIdx.x * blockDim.x + threadIdx.x;
    int lane  = t & 63;
    int chunk = (t >> 6) & 15;
    int rest  = t >> 10;            // bn*48 + tile
    int tile  = rest % 48;
    int bn    = rest / 48;
    int c     = bn * 256 + (chunk >> 1) * 32 + (lane & 31);
    int g     = (c >> 5) & 3;
    int hcol  = ((c >> 7) << 5) | (c & 31);
    int k     = tile * 32 + (chunk & 1) * 16 + (lane >> 5) * 8;
    const float* up = (g == 0) ? Ui : (g == 1) ? Uf : (g == 2) ? Uo : Uc;
    const float* wp = (g == 0) ? Wi : (g == 1) ? Wf : (g == 2) ? Wo : Wc;
    u16x8 o;
    if (k < 512) {
        const float* s = up + (size_t)k * H_DIM + hcol;
        #pragma unroll
        for (int i = 0; i < 8; ++i) o[i] = f2bf(s[(size_t)i * H_DIM]);
    } else {
        const float* s = wp + (size_t)(k - 512) * H_DIM + hcol;
        #pragma unroll
        for (int i = 0; i < 8; ++i) o[i] = f2bf(s[(size_t)i * H_DIM]);
    }
    *(u16x8*)(Bg + (size_t)t * 8) = o;
}

__global__ void cvt_bias(const float* __restrict__ Uib, const float* __restrict__ Ufb,
                         const float* __restrict__ Uob, const float* __restrict__ Ucb,
                         const float* __restrict__ Wib, const float* __restrict__ Wfb,
                         const float* __restrict__ Wob, const float* __restrict__ Wcb,
                         float* __restrict__ bias) {
    int t = blockIdx.x * blockDim.x + threadIdx.x;
    int g = t >> 10, h = t & 1023;
    const float* ub = (g == 0) ? Uib : (g == 1) ? Ufb : (g == 2) ? Uob : Ucb;
    const float* wb = (g == 0) ? Wib : (g == 1) ? Wfb : (g == 2) ? Wob : Wcb;
    bias[t] = ub[h] + wb[h];
}

// ---------------------------------------------------------------------------
// 256x256 GEMM, mfma_f32_32x32x16_bf16, 5-slot ring, CROSS-PHASE PIPELINE:
// phase t: {ds_read tile t+1 -> fr_next ; STAGE tile t+4 ; MFMA tile t from
// fr_cur ; vmcnt(8)+barrier}. MFMA waits only a counted lgkmcnt for LAST
// phase's reads (compiler-inserted), so this phase's 12 reads and 4 glds run
// UNDER the MFMA cluster -> LDS pipe (1156cy) overlaps matrix pipe (1033cy).
// Ring: read slot = tile%5, stage slot = (t+4)%5. Gate vmcnt(8) per phase
// guarantees stage(t+2) retired before phase t+1 reads tile t+2; WAR
// protected by the end-of-(t-1) barrier. Tail gates: 8 -> 4 -> 0.
// ---------------------------------------------------------------------------
__global__ __launch_bounds__(512, 2) void lstm_gemm(
        const unsigned short* __restrict__ Ag, const unsigned short* __restrict__ Bg,
        const float* __restrict__ bias, const float* __restrict__ c_old,
        float* __restrict__ out) {
    __shared__ __align__(1024) char lds[163840];   // 5 slots x 32 KiB

    const int tid = threadIdx.x;
    const int l   = tid & 63;
    const int wv  = tid >> 6;
    const int wm  = wv >> 1;      // 0..3
    const int wn  = wv & 1;       // 0..1

    // XCD-aware swizzle: per XCD 8bm x 4bn chunks
    const int orig = blockIdx.x;
    const int xcd  = orig & 7;
    const int jj   = orig >> 3;
    const int bn   = (xcd & 3) * 4 + (jj & 3);     // 0..15
    const int bm   = (xcd >> 2) * 32 + (jj >> 2);  // 0..63

    // running staging source pointers (advance 8192 elems per staged tile)
    const unsigned short* aCur = Ag + (size_t)bm * 48 * 8192 + (size_t)(wv * 2) * 512 + l * 8;
    const unsigned short* bCur = Bg + (size_t)bn * 48 * 8192 + (size_t)(wv * 2) * 512 + l * 8;

    // in-slot read offsets (lane-varying, constant over loop)
    const int aRdOff = wm * 4096 + l * 16;
    const int bRdOff = 16384 + wn * 8192 + l * 16;

    int rdOff = 0;        // slot byte-offset for next READS (tile%5 * 32768)
    int stOff = 0;        // slot byte-offset for next STAGE

#define GLDS(SRC, DST) __builtin_amdgcn_global_load_lds(                            \
        (const __attribute__((address_space(1))) void*)(SRC),                       \
        (__attribute__((address_space(3))) void*)(DST), 16, 0, 0)

#define STAGE_T() do {                                                              \
    char* _d = (char*)lds + stOff + wv * 2048;                                      \
    GLDS(aCur,       _d);            GLDS(aCur + 512, _d + 1024);                   \
    GLDS(bCur,       _d + 16384);    GLDS(bCur + 512, _d + 16384 + 1024);           \
    aCur += 8192; bCur += 8192;                                                     \
    stOff = (stOff == 131072) ? 0 : stOff + 32768;                                  \
} while (0)

#define READS(FR) do {                                                              \
    const char* _pA = (const char*)lds + rdOff + aRdOff;                            \
    const char* _pB = (const char*)lds + rdOff + bRdOff;                            \
    _Pragma("unroll") for (int mm = 0; mm < 2; ++mm)                                \
        _Pragma("unroll") for (int ks = 0; ks < 2; ++ks)                            \
            FR[mm * 2 + ks] = *(const bf16x8*)(_pA + mm * 2048 + ks * 1024);        \
    _Pragma("unroll") for (int nn = 0; nn < 4; ++nn)                                \
        _Pragma("unroll") for (int ks = 0; ks < 2; ++ks)                            \
            FR[4 + nn * 2 + ks] = *(const bf16x8*)(_pB + nn * 2048 + ks * 1024);    \
    rdOff = (rdOff == 131072) ? 0 : rdOff + 32768;                                  \
} while (0)

    f32x16 acc[2][4] = {};

#define MFMAS(FR) do {                                                              \
    __builtin_amdgcn_s_setprio(1);                                                  \
    _Pragma("unroll") for (int ks = 0; ks < 2; ++ks)                                \
        _Pragma("unroll") for (int mm = 0; mm < 2; ++mm)                            \
            _Pragma("unroll") for (int nn = 0; nn < 4; ++nn)                        \
                acc[mm][nn] = __builtin_amdgcn_mfma_f32_32x32x16_bf16(              \
                    FR[mm * 2 + ks], FR[4 + nn * 2 + ks], acc[mm][nn], 0, 0, 0);    \
    __builtin_amdgcn_s_setprio(0);                                                  \
} while (0)

#define GATE(N) asm volatile("s_waitcnt vmcnt(" #N ")\ns_barrier" ::: "memory")

    bf16x8 fr0[12], fr1[12];

    // ---- prologue: stage tiles 0..3 -> slots 0..3; gate; preload tile 0 ----
    STAGE_T(); STAGE_T(); STAGE_T(); STAGE_T();     // leaves stOff = slot 4
    GATE(8);                                        // tiles 0,1 resident
    READS(fr0);                                     // tile 0 (slot 0); rdOff->slot1

    // ---- main loop: 22 iters x 2 phases = tiles 0..43 ----
    #pragma unroll 1
    for (int i = 0; i < 22; ++i) {
        READS(fr1);          // tile 2i+1
        STAGE_T();           // tile 2i+4
        MFMAS(fr0);          // tile 2i
        GATE(8);
        READS(fr0);          // tile 2i+2
        STAGE_T();           // tile 2i+5
        MFMAS(fr1);          // tile 2i+1
        GATE(8);
    }

    // ---- tail: tiles 44..47 (no more staging; gates tighten 8->4->0) ----
    READS(fr1);  MFMAS(fr0);  GATE(4);   // t=44: MFMA 44, read 45
    READS(fr0);  MFMAS(fr1);  GATE(0);   // t=45: MFMA 45, read 46
    READS(fr1);  MFMAS(fr0);  asm volatile("s_barrier" ::: "memory");  // t=46
    MFMAS(fr1);                           // t=47

    // ---- fused LSTM epilogue: gate = nn (in-lane), hh = (bn*2+wn)*32 + col ----
    const int r31 = l & 31;
    const int h5  = l >> 5;
    const int hh  = (bn * 2 + wn) * 32 + r31;
    const float bi  = bias[hh];
    const float bff = bias[1024 + hh];
    const float bo  = bias[2048 + hh];
    const float bc  = bias[3072 + hh];

    #pragma unroll
    for (int mm = 0; mm < 2; ++mm) {
        const int rb = bm * 256 + wm * 64 + mm * 32 + 4 * h5;
        #pragma unroll
        for (int r = 0; r < 16; ++r) {
            const int row = rb + (r & 3) + 8 * (r >> 2);
            float iv = acc[mm][0][r] + bi;
            float fv = acc[mm][1][r] + bff;
            float ov = acc[mm][2][r] + bo;
            float gv = acc[mm][3][r] + bc;
            float it = 1.f / (1.f + __expf(-iv));
            float ft = 1.f / (1.f + __expf(-fv));
            float ot = 1.f / (1.f + __expf(-ov));
            float gt = 1.f - 2.f / (1.f + __expf(2.f * gv));
            float co = c_old[(size_t)row * H_DIM + hh];
            float cn = it * gt + ft * co;
            float th = 1.f - 2.f / (1.f + __expf(2.f * cn));
            out[(size_t)row * H_DIM + hh] = ot * th;                          // h_new
            out[(size_t)B_ROWS * H_DIM + (size_t)row * H_DIM + hh] = cn;      // c
        }
    }
#undef GATE
#undef MFMAS
#undef READS
#undef STAGE_T
#undef GLDS
}

extern "C" void kernel_launch(void* const* d_in, const int* in_sizes, int n_in,
                              void* d_out, int out_size, void* d_ws, size_t ws_size,
                              hipStream_t stream) {
    const float* x  = (const float*)d_in[0];
    const float* h0 = (const float*)d_in[1];
    const float* c0 = (const float*)d_in[2];
    const float* Uw[4] = {(const float*)d_in[3],  (const float*)d_in[5],
                          (const float*)d_in[7],  (const float*)d_in[9]};
    const float* Ub[4] = {(const float*)d_in[4],  (const float*)d_in[6],
                          (const float*)d_in[8],  (const float*)d_in[10]};
    const float* Ww[4] = {(const float*)d_in[11], (const float*)d_in[13],
                          (const float*)d_in[15], (const float*)d_in[17]};
    const float* Wb[4] = {(const float*)d_in[12], (const float*)d_in[14],
                          (const float*)d_in[16], (const float*)d_in[18]};

    unsigned short* Ag = (unsigned short*)d_ws;                 // 48 MiB
    unsigned short* Bg = Ag + (size_t)B_ROWS * K_TOT;           // 12 MiB
    float* bias        = (float*)(Bg + (size_t)4096 * K_TOT);   // 16 KiB
    float* out         = (float*)d_out;

    cvt_A<<<12288, 256, 0, stream>>>(x, h0, Ag);
    cvt_B<<<3072, 256, 0, stream>>>(Uw[0], Uw[1], Uw[2], Uw[3],
                                    Ww[0], Ww[1], Ww[2], Ww[3], Bg);
    cvt_bias<<<16, 256, 0, stream>>>(Ub[0], Ub[1], Ub[2], Ub[3],
                                     Wb[0], Wb[1], Wb[2], Wb[3], bias);
    lstm_gemm<<<1024, 512, 0, stream>>>(Ag, Bg, bias, c0, out);
}